// Round 2
// baseline (76626.709 us; speedup 1.0000x reference)
//
#include <hip/hip_runtime.h>
#include <hip/hip_cooperative_groups.h>

namespace cg = cooperative_groups;

namespace {
constexpr int kB = 256;   // batch
constexpr int kT = 512;   // time steps
constexpr int kE = 512;   // embed dim
constexpr int kH = 1024;  // hidden dim
constexpr int BB = 32;    // batch rows per block
constexpr int NC = 96;    // gate columns per block (32 hidden x 3 gates)
constexpr int CK = 64;    // K chunk
constexpr int NT = 256;   // threads per block
constexpr int F4H = BB * (CK / 4);                 // 512 float4 for input tile
constexpr int NPF = (BB + NC) * (CK / 4) / NT;     // 8 float4 per thread per chunk
}

// Persistent cooperative GRU kernel, fp32 (no fp32-input MFMA on CDNA4; this
// is the VALU-bound correctness-first baseline).
// Grid: 256 blocks = 8 batch-groups x 32 hidden-groups, 1 block/CU.
// blockIdx = bg*32 + jg  ->  XCD = jg%8: the 8 batch-groups sharing a W slice
// co-locate on one XCD (slice stays L2-resident, ~1.6 MB/XCD).
// Staging uses register-prefetch (issue chunk k+1 during compute of chunk k)
// because 1 wave/SIMD means no TLP to hide VMEM latency.
__global__ void __launch_bounds__(NT, 1)
gru_persist(const int* __restrict__ x, const float* __restrict__ h0,
            const int* __restrict__ seq_len, const float* __restrict__ emb,
            const float* __restrict__ Wih, const float* __restrict__ Whh,
            const float* __restrict__ bih, const float* __restrict__ bhh,
            const float* __restrict__ Wlin, const float* __restrict__ blin,
            float* __restrict__ out, float* __restrict__ ws)
{
    cg::grid_group grid = cg::this_grid();

    __shared__ float h_s[BB][CK + 4];   // input tile (embeds or h); row = 272B, 16B-aligned
    __shared__ float w_s[NC][CK + 4];   // weight tile
    __shared__ float gI[NC][BB + 1];    // gate pre-activations (input side)
    __shared__ float gH[NC][BB + 1];    // gate pre-activations (hidden side)
    __shared__ float red[NT];
    __shared__ int   sx[BB];
    __shared__ int   ssl[BB];

    const int tid = threadIdx.x;
    const int bg  = blockIdx.x >> 5;    // 0..7
    const int jg  = blockIdx.x & 31;    // 0..31
    const int b0  = bg * BB;
    const int j0  = jg * 32;

    // compute mapping: each thread owns 4 batch rows x 3 gate columns
    const int tb = (tid & 7) * 4;
    const int tc = (tid >> 3) * 3;
    // gate mapping: each thread owns 4 batch rows x 1 hidden index
    const int gj = tid & 31;
    const int gb = (tid >> 5) * 4;

    // loop-invariant: weight row ids + biases for this thread's 3 gate columns
    int   wr[3]; float bI[3], bH[3];
    #pragma unroll
    for (int j = 0; j < 3; ++j) {
        int c = tc + j;
        wr[j] = (c >> 5) * kH + j0 + (c & 31);
        bI[j] = bih[wr[j]];
        bH[j] = bhh[wr[j]];
    }

    float* buf0 = ws;
    float* buf1 = ws + (size_t)kB * kH;

    if (tid < BB) ssl[tid] = seq_len[b0 + tid];
    if (jg == 0) {  // init h double-buffer from the input hidden state
        for (int idx = tid; idx < BB * kH; idx += NT) {
            int r = idx >> 10, c = idx & (kH - 1);
            buf0[(size_t)(b0 + r) * kH + c] = h0[(size_t)(b0 + r) * kH + c];
        }
    }
    grid.sync();

    float4 pf[NPF];  // register prefetch buffer (8 x float4 = 32 VGPR in flight)

    // stage: commit prefetch registers into LDS tiles (same idx mapping as issue)
    auto stage_commit = [&]() {
        #pragma unroll
        for (int l = 0; l < NPF; ++l) {
            int idx = l * NT + tid;
            if (idx < F4H) {
                int r = idx >> 4, q = idx & 15;
                *(float4*)&h_s[r][q * 4] = pf[l];
            } else {
                int m = idx - F4H;
                int r = m >> 4, q = m & 15;
                *(float4*)&w_s[r][q * 4] = pf[l];
            }
        }
    };
    auto issue_ih = [&](int k0) {
        #pragma unroll
        for (int l = 0; l < NPF; ++l) {
            int idx = l * NT + tid;
            if (idx < F4H) {
                int r = idx >> 4, q = idx & 15;
                pf[l] = *(const float4*)&emb[(size_t)sx[r] * kE + k0 + q * 4];
            } else {
                int m = idx - F4H;
                int r = m >> 4, q = m & 15;
                int wrow = (r >> 5) * kH + j0 + (r & 31);
                pf[l] = *(const float4*)&Wih[(size_t)wrow * kE + k0 + q * 4];
            }
        }
    };
    auto issue_hh = [&](const float* __restrict__ hc, int k0) {
        #pragma unroll
        for (int l = 0; l < NPF; ++l) {
            int idx = l * NT + tid;
            if (idx < F4H) {
                int r = idx >> 4, q = idx & 15;
                pf[l] = *(const float4*)&hc[(size_t)(b0 + r) * kH + k0 + q * 4];
            } else {
                int m = idx - F4H;
                int r = m >> 4, q = m & 15;
                int wrow = (r >> 5) * kH + j0 + (r & 31);
                pf[l] = *(const float4*)&Whh[(size_t)wrow * kH + k0 + q * 4];
            }
        }
    };
    auto gemm_chunk = [&](float (*acc)[3]) {
        #pragma unroll 2
        for (int kk = 0; kk < CK; kk += 4) {
            float4 hv[4], wv[3];
            #pragma unroll
            for (int i = 0; i < 4; ++i) hv[i] = *(const float4*)&h_s[tb + i][kk];
            #pragma unroll
            for (int j = 0; j < 3; ++j) wv[j] = *(const float4*)&w_s[tc + j][kk];
            #pragma unroll
            for (int i = 0; i < 4; ++i)
                #pragma unroll
                for (int j = 0; j < 3; ++j) {
                    acc[i][j] = fmaf(hv[i].x, wv[j].x, acc[i][j]);
                    acc[i][j] = fmaf(hv[i].y, wv[j].y, acc[i][j]);
                    acc[i][j] = fmaf(hv[i].z, wv[j].z, acc[i][j]);
                    acc[i][j] = fmaf(hv[i].w, wv[j].w, acc[i][j]);
                }
        }
    };

    for (int t = 0; t < kT; ++t) {
        const float* __restrict__ hc = (t & 1) ? buf1 : buf0;  // h after step t-1
        float* __restrict__ hn       = (t & 1) ? buf0 : buf1;  // h after step t

        // ---- output tap: sample b finished at step t-1 iff seq_len == t;
        //      hc == h_{t} == h after consuming seq_len tokens ----
        if (jg == 0 && t > 0) {
            for (int b = 0; b < BB; ++b) {
                if (ssl[b] == t) {   // block-uniform condition (ssl is shared)
                    const float* hr = hc + (size_t)(b0 + b) * kH;
                    float p = 0.f;
                    for (int k = tid; k < kH; k += NT) p += hr[k] * Wlin[k];
                    red[tid] = p;
                    __syncthreads();
                    for (int s = NT / 2; s > 0; s >>= 1) {
                        if (tid < s) red[tid] += red[tid + s];
                        __syncthreads();
                    }
                    if (tid == 0) out[b0 + b] = 1.f / (1.f + expf(-(red[0] + blin[0])));
                    __syncthreads();
                }
            }
        }

        if (tid < BB) {
            int v = x[(size_t)(b0 + tid) * kT + t];
            sx[tid] = (v >= 0 && v < 32000) ? v : 0;  // defensive clamp
        }
        __syncthreads();   // sx visible before prologue issue

        float ai[4][3] = {{0.f}}, ah[4][3] = {{0.f}};
        #pragma unroll
        for (int i = 0; i < 4; ++i)
            #pragma unroll
            for (int j = 0; j < 3; ++j) { ai[i][j] = 0.f; ah[i][j] = 0.f; }

        // ---- gi = emb(x_t) @ Wih^T  (K = 512), software-pipelined ----
        issue_ih(0);
        for (int k0 = 0; k0 < kE; k0 += CK) {
            __syncthreads();                    // prev chunk's compute done
            stage_commit();                     // regs -> LDS (waits vmcnt here)
            if (k0 + CK < kE) issue_ih(k0 + CK);// overlap next loads w/ compute
            __syncthreads();
            gemm_chunk(ai);
        }

        // ---- gh = h @ Whh^T  (K = 1024), software-pipelined ----
        issue_hh(hc, 0);
        for (int k0 = 0; k0 < kH; k0 += CK) {
            __syncthreads();
            stage_commit();
            if (k0 + CK < kH) issue_hh(hc, k0 + CK);
            __syncthreads();
            gemm_chunk(ah);
        }

        // ---- exchange gate pre-activations through LDS (+ biases) ----
        __syncthreads();
        #pragma unroll
        for (int j = 0; j < 3; ++j) {
            int c = tc + j;
            #pragma unroll
            for (int i = 0; i < 4; ++i) {
                gI[c][tb + i] = ai[i][j] + bI[j];
                gH[c][tb + i] = ah[i][j] + bH[j];
            }
        }
        __syncthreads();

        // ---- gates + h_new ----
        #pragma unroll
        for (int i = 0; i < 4; ++i) {
            int b = gb + i;
            float xr = gI[gj][b] + gH[gj][b];
            float xz = gI[32 + gj][b] + gH[32 + gj][b];
            float rr = 1.f / (1.f + expf(-xr));
            float zz = 1.f / (1.f + expf(-xz));
            float nn = tanhf(gI[64 + gj][b] + rr * gH[64 + gj][b]);
            size_t off = (size_t)(b0 + b) * kH + j0 + gj;
            float hold = hc[off];
            float hv = (1.f - zz) * nn + zz * hold;
            hn[off] = hv;
            if (t == kT - 1) out[kB + off] = hv;  // h_final region of d_out
        }

        __threadfence();
        grid.sync();
    }

    // ---- output tap for samples with seq_len == T ----
    if (jg == 0) {
        const float* hfin = buf0;  // kT = 512 even: last write landed in buf0
        for (int b = 0; b < BB; ++b) {
            if (ssl[b] == kT) {
                const float* hr = hfin + (size_t)(b0 + b) * kH;
                float p = 0.f;
                for (int k = tid; k < kH; k += NT) p += hr[k] * Wlin[k];
                red[tid] = p;
                __syncthreads();
                for (int s = NT / 2; s > 0; s >>= 1) {
                    if (tid < s) red[tid] += red[tid + s];
                    __syncthreads();
                }
                if (tid == 0) out[b0 + b] = 1.f / (1.f + expf(-(red[0] + blin[0])));
                __syncthreads();
            }
        }
    }
}

extern "C" void kernel_launch(void* const* d_in, const int* in_sizes, int n_in,
                              void* d_out, int out_size, void* d_ws, size_t ws_size,
                              hipStream_t stream) {
    const int*   x    = (const int*)  d_in[0];
    const float* h0   = (const float*)d_in[1];
    const int*   sl   = (const int*)  d_in[2];
    const float* emb  = (const float*)d_in[3];
    const float* Wih  = (const float*)d_in[4];
    const float* Whh  = (const float*)d_in[5];
    const float* bih  = (const float*)d_in[6];
    const float* bhh  = (const float*)d_in[7];
    const float* Wlin = (const float*)d_in[8];
    const float* blin = (const float*)d_in[9];
    float* out = (float*)d_out;
    float* ws  = (float*)d_ws;   // needs 2 MB for the h double-buffer

    void* args[] = {&x, &h0, &sl, &emb, &Wih, &Whh, &bih, &bhh, &Wlin, &blin, &out, &ws};
    hipLaunchCooperativeKernel((void*)gru_persist, dim3(256), dim3(NT), args, 0, stream);
}

// Round 3
// 58320.715 us; speedup vs baseline: 1.3139x; 1.3139x over previous
//
#include <hip/hip_runtime.h>

namespace {
constexpr int kB = 256;   // batch
constexpr int kT = 512;   // time steps
constexpr int kE = 512;   // embed dim
constexpr int kH = 1024;  // hidden dim
constexpr int BB = 16;    // batch rows per block
constexpr int NC = 96;    // gate columns per block (32 hidden x 3 gates)
constexpr int CK = 64;    // K chunk
constexpr int NT = 256;   // threads per block
constexpr int F4H = BB * (CK / 4);              // 256 float4 for input tile
constexpr int NPF = (BB + NC) * (CK / 4) / NT;  // 7 float4 per thread per chunk
constexpr int VOCAB = 32000;
}

// One GRU time step. Grid: 512 blocks = 16 batch-groups x 32 hidden-groups
// (2 blocks/CU -> 2 waves/SIMD of TLP; staging L2 traffic/CU (~9.4us) hides
// under FMA issue (~15.4us)). Kernel boundary replaces grid.sync() -- round-2
// profile showed the cooperative version burned ~90% of time in sync/latency
// (VALUBusy 17.7%, all pipes idle).
// blockIdx = bg*32 + jg -> XCD = jg%8: the 16 blocks sharing a weight slice
// co-locate on one XCD (slice stays L2-resident, ~2.4 MB/XCD working set).
__global__ void __launch_bounds__(NT, 2)
gru_step(const int* __restrict__ x, const int* __restrict__ seq_len,
         const float* __restrict__ emb, const float* __restrict__ Wih,
         const float* __restrict__ Whh, const float* __restrict__ bih,
         const float* __restrict__ bhh, const float* __restrict__ Wlin,
         const float* __restrict__ blin, const float* __restrict__ hc,
         float* __restrict__ hn, float* __restrict__ out, int t)
{
    __shared__ float h_s[BB][CK + 4];   // input tile; row 272B (17x16B): f4-aligned,
    __shared__ float w_s[NC][CK + 4];   // rows spread 2-way over banks (free)
    __shared__ float gI[NC][BB + 1];
    __shared__ float gH[NC][BB + 1];
    __shared__ float red[NT];
    __shared__ int   sx[BB];
    __shared__ int   ssl[BB];

    const int tid = threadIdx.x;
    const int bg  = blockIdx.x >> 5;    // 0..15
    const int jg  = blockIdx.x & 31;    // 0..31
    const int b0  = bg * BB;
    const int j0  = jg * 32;

    // compute mapping: 2 batch rows x 3 gate columns per thread
    const int tb = (tid & 7) * 2;
    const int tc = (tid >> 3) * 3;
    // gate mapping: 2 batch rows x 1 hidden index per thread
    const int gj = tid & 31;
    const int gb = (tid >> 5) * 2;

    if (tid < BB) {
        ssl[tid] = seq_len[b0 + tid];
        int v = x[(size_t)(b0 + tid) * kT + t];
        sx[tid] = (v >= 0 && v < VOCAB) ? v : 0;  // defensive clamp
    }
    __syncthreads();

    // ---- output tap: sample b needs h_{ssl[b]}; hc here IS h_t, so tap when
    //      ssl == t (t >= 1; ssl==kT handled by epilogue kernel) ----
    if (jg == 0 && t > 0) {
        for (int b = 0; b < BB; ++b) {
            if (ssl[b] == t) {   // block-uniform (ssl is shared)
                const float* hr = hc + (size_t)(b0 + b) * kH;
                float p = 0.f;
                for (int k = tid; k < kH; k += NT) p += hr[k] * Wlin[k];
                red[tid] = p;
                __syncthreads();
                for (int s = NT / 2; s > 0; s >>= 1) {
                    if (tid < s) red[tid] += red[tid + s];
                    __syncthreads();
                }
                if (tid == 0) out[b0 + b] = 1.f / (1.f + expf(-(red[0] + blin[0])));
                __syncthreads();
            }
        }
    }

    // biases for this thread's 3 gate columns
    float bI[3], bH[3];
    #pragma unroll
    for (int j = 0; j < 3; ++j) {
        int c = tc + j;
        int wrow = (c >> 5) * kH + j0 + (c & 31);
        bI[j] = bih[wrow];
        bH[j] = bhh[wrow];
    }

    float4 pf[NPF];  // register prefetch: issue chunk k+1 during compute of k

    auto stage_commit = [&]() {
        #pragma unroll
        for (int l = 0; l < NPF; ++l) {
            int idx = l * NT + tid;
            if (idx < F4H) {
                int r = idx >> 4, q = idx & 15;
                *(float4*)&h_s[r][q * 4] = pf[l];
            } else {
                int m = idx - F4H;
                int r = m >> 4, q = m & 15;
                *(float4*)&w_s[r][q * 4] = pf[l];
            }
        }
    };
    auto issue_ih = [&](int k0) {
        #pragma unroll
        for (int l = 0; l < NPF; ++l) {
            int idx = l * NT + tid;
            if (idx < F4H) {
                int r = idx >> 4, q = idx & 15;
                pf[l] = *(const float4*)&emb[(size_t)sx[r] * kE + k0 + q * 4];
            } else {
                int m = idx - F4H;
                int r = m >> 4, q = m & 15;
                int wrow = (r >> 5) * kH + j0 + (r & 31);
                pf[l] = *(const float4*)&Wih[(size_t)wrow * kE + k0 + q * 4];
            }
        }
    };
    auto issue_hh = [&](int k0) {
        #pragma unroll
        for (int l = 0; l < NPF; ++l) {
            int idx = l * NT + tid;
            if (idx < F4H) {
                int r = idx >> 4, q = idx & 15;
                pf[l] = *(const float4*)&hc[(size_t)(b0 + r) * kH + k0 + q * 4];
            } else {
                int m = idx - F4H;
                int r = m >> 4, q = m & 15;
                int wrow = (r >> 5) * kH + j0 + (r & 31);
                pf[l] = *(const float4*)&Whh[(size_t)wrow * kH + k0 + q * 4];
            }
        }
    };
    auto gemm_chunk = [&](float (*acc)[3]) {
        #pragma unroll 2
        for (int kk = 0; kk < CK; kk += 4) {
            float4 hv[2], wv[3];
            #pragma unroll
            for (int i = 0; i < 2; ++i) hv[i] = *(const float4*)&h_s[tb + i][kk];
            #pragma unroll
            for (int j = 0; j < 3; ++j) wv[j] = *(const float4*)&w_s[tc + j][kk];
            #pragma unroll
            for (int i = 0; i < 2; ++i)
                #pragma unroll
                for (int j = 0; j < 3; ++j) {
                    acc[i][j] = fmaf(hv[i].x, wv[j].x, acc[i][j]);
                    acc[i][j] = fmaf(hv[i].y, wv[j].y, acc[i][j]);
                    acc[i][j] = fmaf(hv[i].z, wv[j].z, acc[i][j]);
                    acc[i][j] = fmaf(hv[i].w, wv[j].w, acc[i][j]);
                }
        }
    };

    float ai[2][3], ah[2][3];
    #pragma unroll
    for (int i = 0; i < 2; ++i)
        #pragma unroll
        for (int j = 0; j < 3; ++j) { ai[i][j] = 0.f; ah[i][j] = 0.f; }

    // ---- gi = emb(x_t) @ Wih^T  (K = 512), software-pipelined ----
    issue_ih(0);
    for (int k0 = 0; k0 < kE; k0 += CK) {
        __syncthreads();
        stage_commit();
        if (k0 + CK < kE) issue_ih(k0 + CK);
        __syncthreads();
        gemm_chunk(ai);
    }

    // ---- gh = h @ Whh^T  (K = 1024), software-pipelined ----
    issue_hh(0);
    for (int k0 = 0; k0 < kH; k0 += CK) {
        __syncthreads();
        stage_commit();
        if (k0 + CK < kH) issue_hh(k0 + CK);
        __syncthreads();
        gemm_chunk(ah);
    }

    // ---- exchange gate pre-activations through LDS (+ biases) ----
    __syncthreads();
    #pragma unroll
    for (int j = 0; j < 3; ++j) {
        int c = tc + j;
        #pragma unroll
        for (int i = 0; i < 2; ++i) {
            gI[c][tb + i] = ai[i][j] + bI[j];
            gH[c][tb + i] = ah[i][j] + bH[j];
        }
    }
    __syncthreads();

    // ---- gates + h_new ----
    #pragma unroll
    for (int i = 0; i < 2; ++i) {
        int b = gb + i;
        float xr = gI[gj][b] + gH[gj][b];
        float xz = gI[32 + gj][b] + gH[32 + gj][b];
        float rr = 1.f / (1.f + expf(-xr));
        float zz = 1.f / (1.f + expf(-xz));
        float nn = tanhf(gI[64 + gj][b] + rr * gH[64 + gj][b]);
        size_t off = (size_t)(b0 + b) * kH + j0 + gj;
        float hold = hc[off];
        hn[off] = (1.f - zz) * nn + zz * hold;
    }
}

// Epilogue: h_final copy + taps for samples that ran the full T steps.
// Grid: one block per batch sample.
__global__ void __launch_bounds__(NT)
gru_final(const float* __restrict__ hf, const int* __restrict__ seq_len,
          const float* __restrict__ Wlin, const float* __restrict__ blin,
          float* __restrict__ out)
{
    __shared__ float red[NT];
    const int b = blockIdx.x, tid = threadIdx.x;
    const float* hr = hf + (size_t)b * kH;

    float4 v = *(const float4*)&hr[tid * 4];
    *(float4*)&out[kB + (size_t)b * kH + tid * 4] = v;  // h_final region

    if (seq_len[b] == kT) {
        float4 w = *(const float4*)&Wlin[tid * 4];
        red[tid] = v.x * w.x + v.y * w.y + v.z * w.z + v.w * w.w;
        __syncthreads();
        for (int s = NT / 2; s > 0; s >>= 1) {
            if (tid < s) red[tid] += red[tid + s];
            __syncthreads();
        }
        if (tid == 0) out[b] = 1.f / (1.f + expf(-(red[0] + blin[0])));
    }
}

extern "C" void kernel_launch(void* const* d_in, const int* in_sizes, int n_in,
                              void* d_out, int out_size, void* d_ws, size_t ws_size,
                              hipStream_t stream) {
    (void)in_sizes; (void)n_in; (void)out_size; (void)ws_size;
    const int*   x    = (const int*)  d_in[0];
    const float* h0   = (const float*)d_in[1];
    const int*   sl   = (const int*)  d_in[2];
    const float* emb  = (const float*)d_in[3];
    const float* Wih  = (const float*)d_in[4];
    const float* Whh  = (const float*)d_in[5];
    const float* bih  = (const float*)d_in[6];
    const float* bhh  = (const float*)d_in[7];
    const float* Wlin = (const float*)d_in[8];
    const float* blin = (const float*)d_in[9];
    float* out  = (float*)d_out;
    float* buf0 = (float*)d_ws;                       // h double-buffer: 2 MB
    float* buf1 = (float*)d_ws + (size_t)kB * kH;

    for (int t = 0; t < kT; ++t) {
        // step t reads h_t, writes h_{t+1}: h_1 -> buf1, h_2 -> buf0, ...
        const float* hc = (t == 0) ? h0 : ((t & 1) ? buf1 : buf0);
        float* hn = ((t + 1) & 1) ? buf1 : buf0;
        hipLaunchKernelGGL(gru_step, dim3(512), dim3(NT), 0, stream,
                           x, sl, emb, Wih, Whh, bih, bhh, Wlin, blin,
                           hc, hn, out, t);
    }
    // h_{512} lands in buf0 (kT even)
    hipLaunchKernelGGL(gru_final, dim3(kB), dim3(NT), 0, stream,
                       buf0, sl, Wlin, blin, out);
}